// Round 1
// baseline (203.079 us; speedup 1.0000x reference)
//
#include <hip/hip_runtime.h>

#define NH   12
#define ND   64
#define NSEQ 4096
#define NIT  16
#define MM   256   // rows per iteration chunk

// LDS layout (bytes)
#define X_P  72    // X pitch (bf16 elems), 256 x 72
#define T_P  264   // XT/ET pitch, 64 x 264
#define W_P  72    // WBT pitch, 64 x 72
#define WF_P 65    // W f32 pitch, 64 x 65

#define SM_X    0
#define SM_XT   36864
#define SM_ET   70656
#define SM_WBT  104448
#define SM_WF   113664
#define SM_TOTAL 130304

typedef __bf16 bf16_t;
typedef bf16_t bf16x8 __attribute__((ext_vector_type(8)));
typedef float  f32x4  __attribute__((ext_vector_type(4)));

__device__ __forceinline__ unsigned short f2bf(float f) {
    union { float f; unsigned u; } v; v.f = f;
    return (unsigned short)((v.u + 0x7FFFu + ((v.u >> 16) & 1u)) >> 16);
}

extern "C" __global__ void __launch_bounds__(1024)
ttt_fused(const float* __restrict__ qg, const float* __restrict__ kg,
          const float* __restrict__ vg, const float* __restrict__ Wi,
          float* __restrict__ outg)
{
    extern __shared__ char smem[];
    unsigned short* X   = (unsigned short*)(smem + SM_X);    // x chunk row-major bf16
    unsigned short* XT  = (unsigned short*)(smem + SM_XT);   // x_tr transposed (d-major)
    unsigned short* ET  = (unsigned short*)(smem + SM_ET);   // err transposed (e-major)
    unsigned short* WBT = (unsigned short*)(smem + SM_WBT);  // W transposed bf16 (WBT[n][k]=W[k][n])
    float*          WF  = (float*)(smem + SM_WF);            // W fp32 master

    const int tid  = threadIdx.x;
    const int lane = tid & 63;
    const int wv   = tid >> 6;      // wave 0..15
    const int g    = lane >> 4;     // 0..3
    const int ln   = lane & 15;     // 0..15

    const int bh = blockIdx.x;
    const int b  = bh / NH;
    const int h  = bh - b * NH;

    const float* kb = kg + (size_t)bh * NSEQ * ND;
    const float* vb = vg + (size_t)bh * NSEQ * ND;
    const float* qb = qg + (size_t)bh * NSEQ * ND;
    float* ob = outg + (size_t)b * NSEQ * (NH * ND) + h * ND;

    // ---- prologue: W_init -> WF (f32) and WBT (bf16, transposed)
    {
        const float4* wp = (const float4*)(Wi + (size_t)h * ND * ND);
        float4 w4 = wp[tid];               // 1024 threads cover 4096 f32
        int r = tid >> 4;                  // W row (k), 0..63
        int c = (tid & 15) << 2;           // W col (n)
        float* wf = &WF[r * WF_P + c];
        wf[0] = w4.x; wf[1] = w4.y; wf[2] = w4.z; wf[3] = w4.w;
        WBT[(c + 0) * W_P + r] = f2bf(w4.x);
        WBT[(c + 1) * W_P + r] = f2bf(w4.y);
        WBT[(c + 2) * W_P + r] = f2bf(w4.z);
        WBT[(c + 3) * W_P + r] = f2bf(w4.w);
    }
    // ---- stage x_tr(0) -> X, XT
    float4 sreg[4];
    {
        const float4* p4 = (const float4*)kb;
        #pragma unroll
        for (int i = 0; i < 4; ++i) sreg[i] = p4[tid + (i << 10)];
        #pragma unroll
        for (int i = 0; i < 4; ++i) {
            int f = tid + (i << 10);
            int r = f >> 4, c = (f & 15) << 2;
            ushort4 pk;
            pk.x = f2bf(sreg[i].x); pk.y = f2bf(sreg[i].y);
            pk.z = f2bf(sreg[i].z); pk.w = f2bf(sreg[i].w);
            *(ushort4*)&X[r * X_P + c] = pk;
            XT[(c + 0) * T_P + r] = pk.x;
            XT[(c + 1) * T_P + r] = pk.y;
            XT[(c + 2) * T_P + r] = pk.z;
            XT[(c + 3) * T_P + r] = pk.w;
        }
    }

    const int r0 = wv << 4;   // wave's 16-row slice of the 256-row chunk
    const float scale = 1.0f / 16384.0f;  // LR / (m*D)

    for (int it = 0; it < NIT; ++it) {
        __syncthreads();   // (1) X/XT (x_tr) and WBT ready

        // ======== Phase A: errT = W^T * x_tr^T  - y^T  -> ET (bf16)
        {
            float4 yv[4];
            const float* yrow = vb + ((size_t)(it * MM) + r0 + ln) * ND + (g << 2);
            #pragma unroll
            for (int e = 0; e < 4; ++e)
                yv[e] = *(const float4*)(yrow + (e << 4));

            bf16x8 xb[2];
            #pragma unroll
            for (int kx = 0; kx < 2; ++kx)
                xb[kx] = *(const bf16x8*)&X[(r0 + ln) * X_P + (kx << 5) + (g << 3)];

            #pragma unroll
            for (int e = 0; e < 4; ++e) {
                f32x4 acc = {0.f, 0.f, 0.f, 0.f};
                #pragma unroll
                for (int kx = 0; kx < 2; ++kx) {
                    bf16x8 af = *(const bf16x8*)&WBT[((e << 4) + ln) * W_P + (kx << 5) + (g << 3)];
                    acc = __builtin_amdgcn_mfma_f32_16x16x32_bf16(af, xb[kx], acc, 0, 0, 0);
                }
                int rr = (e << 4) + (g << 2);
                ET[(rr + 0) * T_P + r0 + ln] = f2bf(acc[0] - yv[e].x);
                ET[(rr + 1) * T_P + r0 + ln] = f2bf(acc[1] - yv[e].y);
                ET[(rr + 2) * T_P + r0 + ln] = f2bf(acc[2] - yv[e].z);
                ET[(rr + 3) * T_P + r0 + ln] = f2bf(acc[3] - yv[e].w);
            }
        }

        // issue x_te global loads (consumed after Phase B)
        {
            const float4* p4 = (const float4*)(qb + (size_t)it * MM * ND);
            #pragma unroll
            for (int i = 0; i < 4; ++i) sreg[i] = p4[tid + (i << 10)];
        }

        __syncthreads();   // (2) ET complete; all waves done reading X

        // ======== Phase B: grad = x_tr^T * err ; W -= grad/16384 ; refresh WBT
        {
            const int d0 = (wv >> 2) << 4;
            const int e0 = (wv & 3) << 4;
            f32x4 ga = {0.f, 0.f, 0.f, 0.f};
            #pragma unroll
            for (int kx = 0; kx < 8; ++kx) {
                bf16x8 af = *(const bf16x8*)&XT[(d0 + ln) * T_P + (kx << 5) + (g << 3)];
                bf16x8 bf = *(const bf16x8*)&ET[(e0 + ln) * T_P + (kx << 5) + (g << 3)];
                ga = __builtin_amdgcn_mfma_f32_16x16x32_bf16(af, bf, ga, 0, 0, 0);
            }
            ushort4 wq;
            unsigned short* wqp = (unsigned short*)&wq;
            #pragma unroll
            for (int j = 0; j < 4; ++j) {
                int r = d0 + (g << 2) + j;
                float nw = WF[r * WF_P + e0 + ln] - scale * ga[j];
                WF[r * WF_P + e0 + ln] = nw;
                wqp[j] = f2bf(nw);
            }
            *(ushort4*)&WBT[(e0 + ln) * W_P + d0 + (g << 2)] = wq;
        }

        // store x_te -> X (X free since barrier (2); hidden vmcnt under Phase B)
        #pragma unroll
        for (int i = 0; i < 4; ++i) {
            int f = tid + (i << 10);
            int r = f >> 4, c = (f & 15) << 2;
            ushort4 pk;
            pk.x = f2bf(sreg[i].x); pk.y = f2bf(sreg[i].y);
            pk.z = f2bf(sreg[i].z); pk.w = f2bf(sreg[i].w);
            *(ushort4*)&X[r * X_P + c] = pk;
        }

        __syncthreads();   // (3) X=x_te and WBT=W' ready

        // issue next x_tr loads (consumed after barrier (4))
        if (it + 1 < NIT) {
            const float4* p4 = (const float4*)(kb + (size_t)(it + 1) * MM * ND);
            #pragma unroll
            for (int i = 0; i < 4; ++i) sreg[i] = p4[tid + (i << 10)];
        }

        // ======== Phase C: out = x_te * W'  -> global
        {
            bf16x8 afr[2];
            #pragma unroll
            for (int kx = 0; kx < 2; ++kx)
                afr[kx] = *(const bf16x8*)&X[(r0 + ln) * X_P + (kx << 5) + (g << 3)];
            #pragma unroll
            for (int e = 0; e < 4; ++e) {
                f32x4 oc = {0.f, 0.f, 0.f, 0.f};
                #pragma unroll
                for (int kx = 0; kx < 2; ++kx) {
                    bf16x8 bf = *(const bf16x8*)&WBT[((e << 4) + ln) * W_P + (kx << 5) + (g << 3)];
                    oc = __builtin_amdgcn_mfma_f32_16x16x32_bf16(afr[kx], bf, oc, 0, 0, 0);
                }
                #pragma unroll
                for (int j = 0; j < 4; ++j) {
                    ob[((size_t)(it * MM) + r0 + (g << 2) + j) * (NH * ND) + (e << 4) + ln] = oc[j];
                }
            }
        }

        __syncthreads();   // (4) everyone done reading X/XT

        if (it + 1 < NIT) {
            #pragma unroll
            for (int i = 0; i < 4; ++i) {
                int f = tid + (i << 10);
                int r = f >> 4, c = (f & 15) << 2;
                ushort4 pk;
                pk.x = f2bf(sreg[i].x); pk.y = f2bf(sreg[i].y);
                pk.z = f2bf(sreg[i].z); pk.w = f2bf(sreg[i].w);
                *(ushort4*)&X[r * X_P + c] = pk;
                XT[(c + 0) * T_P + r] = pk.x;
                XT[(c + 1) * T_P + r] = pk.y;
                XT[(c + 2) * T_P + r] = pk.z;
                XT[(c + 3) * T_P + r] = pk.w;
            }
        }
    }
}

extern "C" void kernel_launch(void* const* d_in, const int* in_sizes, int n_in,
                              void* d_out, int out_size, void* d_ws, size_t ws_size,
                              hipStream_t stream) {
    const float* q  = (const float*)d_in[0];
    const float* k  = (const float*)d_in[1];
    const float* v  = (const float*)d_in[2];
    const float* Wi = (const float*)d_in[3];
    float* out = (float*)d_out;

    int grid = in_sizes[0] / (NSEQ * ND);   // B * H = 192
    hipFuncSetAttribute((const void*)ttt_fused,
                        hipFuncAttributeMaxDynamicSharedMemorySize, SM_TOTAL);
    hipLaunchKernelGGL(ttt_fused, dim3(grid), dim3(1024), SM_TOTAL, stream,
                       q, k, v, Wi, out);
}

// Round 2
// 182.446 us; speedup vs baseline: 1.1131x; 1.1131x over previous
//
#include <hip/hip_runtime.h>

#define NH   12
#define ND   64
#define NSEQ 4096
#define NIT  16
#define MM   256   // rows per iteration chunk

// LDS layout (bf16 element pitches; all row strides ≡ 4 mod 32 dwords → ≤2-way bank alias)
#define X_P  72    // X pitch, 256 x 72 (x_tr row-major)
#define T_P  264   // XT/ET pitch, 64 x 264 (transposed, k=m contiguous)
#define W_P  72    // WBT pitch, 64 x 72 (W transposed bf16: WBT[e][d] = W[d][e])

#define SM_X    0
#define SM_XT   36864
#define SM_ET   70656
#define SM_WBT  104448
#define SM_TOTAL 113664

typedef __bf16 bf16_t;
typedef bf16_t bf16x8 __attribute__((ext_vector_type(8)));
typedef float  f32x4  __attribute__((ext_vector_type(4)));

__device__ __forceinline__ unsigned short f2bf(float f) {
    union { float f; unsigned u; } v; v.f = f;
    return (unsigned short)((v.u + 0x7FFFu + ((v.u >> 16) & 1u)) >> 16);
}

__device__ __forceinline__ bf16x8 pack8(float4 a, float4 b) {
    union { unsigned short u[8]; bf16x8 v; } r;
    r.u[0] = f2bf(a.x); r.u[1] = f2bf(a.y); r.u[2] = f2bf(a.z); r.u[3] = f2bf(a.w);
    r.u[4] = f2bf(b.x); r.u[5] = f2bf(b.y); r.u[6] = f2bf(b.z); r.u[7] = f2bf(b.w);
    return r.v;
}

// Barrier that drains ONLY LDS ops; global loads/stores stay in flight across it.
// asm "memory" clobbers pin memory ops on their side of the barrier.
__device__ __forceinline__ void barrier_lds() {
    asm volatile("s_waitcnt lgkmcnt(0)" ::: "memory");
    __builtin_amdgcn_s_barrier();
    asm volatile("" ::: "memory");
}

extern "C" __global__ void __launch_bounds__(1024)
ttt_fused(const float* __restrict__ qg, const float* __restrict__ kg,
          const float* __restrict__ vg, const float* __restrict__ Wi,
          float* __restrict__ outg)
{
    extern __shared__ char smem[];
    unsigned short* X   = (unsigned short*)(smem + SM_X);    // x_tr row-major bf16
    unsigned short* XT  = (unsigned short*)(smem + SM_XT);   // x_tr transposed (d-major)
    unsigned short* ET  = (unsigned short*)(smem + SM_ET);   // err transposed (e-major)
    unsigned short* WBT = (unsigned short*)(smem + SM_WBT);  // W transposed bf16

    const int tid  = threadIdx.x;
    const int lane = tid & 63;
    const int wv   = tid >> 6;      // wave 0..15
    const int g    = lane >> 4;     // 0..3
    const int ln   = lane & 15;     // 0..15

    const int bh = blockIdx.x;
    const int b  = bh / NH;
    const int h  = bh - b * NH;

    const float* kb = kg + (size_t)bh * NSEQ * ND;
    const float* vb = vg + (size_t)bh * NSEQ * ND;
    const float* qb = qg + (size_t)bh * NSEQ * ND;
    float* ob = outg + (size_t)b * NSEQ * (NH * ND) + h * ND;

    const int r0 = wv << 4;          // wave's 16-row slice of the 256-row chunk
    const int d0 = (wv >> 2) << 4;   // wave's W-chunk (Phase B tile)
    const int e0 = (wv & 3) << 4;
    const float scale = 1.0f / 16384.0f;  // LR / (m*D)

    // ---- prologue: per-wave W f32 chunk -> regs; full W -> WBT (bf16, transposed)
    float wf[4];   // wf[j] = W[d0 + 4g + j][e0 + ln]  (wave-private chunk)
    {
        const float* wp = Wi + (size_t)h * ND * ND;
        ushort4 wq; unsigned short* wqp = (unsigned short*)&wq;
        #pragma unroll
        for (int j = 0; j < 4; ++j) {
            wf[j] = wp[(size_t)(d0 + (g << 2) + j) * ND + e0 + ln];
            wqp[j] = f2bf(wf[j]);
        }
        *(ushort4*)&WBT[(e0 + ln) * W_P + d0 + (g << 2)] = wq;
    }

    // ---- stage x_tr(0) -> X, XT; prefetch v(0) (fragment layout)
    float4 sreg[4];
    {
        const float4* p4 = (const float4*)kb;
        #pragma unroll
        for (int i = 0; i < 4; ++i) sreg[i] = p4[tid + (i << 10)];
    }
    float4 vr[4];
    {
        const float* yrow = vb + (size_t)(r0 + ln) * ND + (g << 2);
        #pragma unroll
        for (int e = 0; e < 4; ++e) vr[e] = *(const float4*)(yrow + (e << 4));
    }
    #pragma unroll
    for (int i = 0; i < 4; ++i) {
        int f = tid + (i << 10);
        int r = f >> 4, c = (f & 15) << 2;
        ushort4 pk;
        pk.x = f2bf(sreg[i].x); pk.y = f2bf(sreg[i].y);
        pk.z = f2bf(sreg[i].z); pk.w = f2bf(sreg[i].w);
        *(ushort4*)&X[r * X_P + c] = pk;
        XT[(c + 0) * T_P + r] = pk.x;
        XT[(c + 1) * T_P + r] = pk.y;
        XT[(c + 2) * T_P + r] = pk.z;
        XT[(c + 3) * T_P + r] = pk.w;
    }

    barrier_lds();   // X/XT/WBT ready

    // W fragments in registers: serve as MFMA-A in Phase A, MFMA-B in Phase C
    bf16x8 wfrag[4][2];
    #pragma unroll
    for (int e = 0; e < 4; ++e)
        #pragma unroll
        for (int kx = 0; kx < 2; ++kx)
            wfrag[e][kx] = *(const bf16x8*)&WBT[((e << 4) + ln) * W_P + (kx << 5) + (g << 3)];

    for (int it = 0; it < NIT; ++it) {
        // ======== Phase A: errT = W^T·x_tr^T - y^T -> ET
        // issue x_te(q) loads now (consumed in Phase C, 2 phases away)
        float4 qr[4];
        {
            const float* qrow = qb + ((size_t)(it * MM) + r0 + ln) * ND;
            #pragma unroll
            for (int kx = 0; kx < 2; ++kx) {
                qr[kx * 2 + 0] = *(const float4*)(qrow + (kx << 5) + (g << 3));
                qr[kx * 2 + 1] = *(const float4*)(qrow + (kx << 5) + (g << 3) + 4);
            }
        }
        {
            bf16x8 xb[2];
            #pragma unroll
            for (int kx = 0; kx < 2; ++kx)
                xb[kx] = *(const bf16x8*)&X[(r0 + ln) * X_P + (kx << 5) + (g << 3)];
            #pragma unroll
            for (int e = 0; e < 4; ++e) {
                f32x4 acc = {0.f, 0.f, 0.f, 0.f};
                #pragma unroll
                for (int kx = 0; kx < 2; ++kx)
                    acc = __builtin_amdgcn_mfma_f32_16x16x32_bf16(wfrag[e][kx], xb[kx], acc, 0, 0, 0);
                int rr = (e << 4) + (g << 2);
                ET[(rr + 0) * T_P + r0 + ln] = f2bf(acc[0] - vr[e].x);
                ET[(rr + 1) * T_P + r0 + ln] = f2bf(acc[1] - vr[e].y);
                ET[(rr + 2) * T_P + r0 + ln] = f2bf(acc[2] - vr[e].z);
                ET[(rr + 3) * T_P + r0 + ln] = f2bf(acc[3] - vr[e].w);
            }
        }

        barrier_lds();   // (B) ET ready; Phase A X-reads drained

        // issue k(it+1), v(it+1) loads (consumed at staging / next Phase A)
        if (it + 1 < NIT) {
            const float4* p4 = (const float4*)(kb + (size_t)(it + 1) * MM * ND);
            #pragma unroll
            for (int i = 0; i < 4; ++i) sreg[i] = p4[tid + (i << 10)];
            const float* yrow = vb + ((size_t)((it + 1) * MM) + r0 + ln) * ND + (g << 2);
            #pragma unroll
            for (int e = 0; e < 4; ++e) vr[e] = *(const float4*)(yrow + (e << 4));
        }

        // ======== Phase B: grad = x_tr^T·err ; W -= grad/16384 (W f32 in regs) ; WBT refresh
        {
            f32x4 ga = {0.f, 0.f, 0.f, 0.f};
            #pragma unroll
            for (int kx = 0; kx < 8; ++kx) {
                bf16x8 af = *(const bf16x8*)&XT[(d0 + ln) * T_P + (kx << 5) + (g << 3)];
                bf16x8 bf = *(const bf16x8*)&ET[(e0 + ln) * T_P + (kx << 5) + (g << 3)];
                ga = __builtin_amdgcn_mfma_f32_16x16x32_bf16(af, bf, ga, 0, 0, 0);
            }
            ushort4 wq; unsigned short* wqp = (unsigned short*)&wq;
            #pragma unroll
            for (int j = 0; j < 4; ++j) {
                wf[j] -= scale * ga[j];
                wqp[j] = f2bf(wf[j]);
            }
            *(ushort4*)&WBT[(e0 + ln) * W_P + d0 + (g << 2)] = wq;
        }

        barrier_lds();   // (C) WBT = W' ready; Phase B XT/ET reads drained

        // refresh W' fragments (used by Phase C now and Phase A next iter)
        #pragma unroll
        for (int e = 0; e < 4; ++e)
            #pragma unroll
            for (int kx = 0; kx < 2; ++kx)
                wfrag[e][kx] = *(const bf16x8*)&WBT[((e << 4) + ln) * W_P + (kx << 5) + (g << 3)];

        // ======== Phase C: out = x_te·W' -> global (x_te straight from q regs)
        {
            bf16x8 afr[2];
            afr[0] = pack8(qr[0], qr[1]);
            afr[1] = pack8(qr[2], qr[3]);
            #pragma unroll
            for (int e = 0; e < 4; ++e) {
                f32x4 oc = {0.f, 0.f, 0.f, 0.f};
                #pragma unroll
                for (int kx = 0; kx < 2; ++kx)
                    oc = __builtin_amdgcn_mfma_f32_16x16x32_bf16(afr[kx], wfrag[e][kx], oc, 0, 0, 0);
                #pragma unroll
                for (int j = 0; j < 4; ++j)
                    ob[((size_t)(it * MM) + r0 + (g << 2) + j) * (NH * ND) + (e << 4) + ln] = oc[j];
            }
        }

        // stage x_tr(it+1) -> X, XT (k loads issued a full phase ago)
        if (it + 1 < NIT) {
            #pragma unroll
            for (int i = 0; i < 4; ++i) {
                int f = tid + (i << 10);
                int r = f >> 4, c = (f & 15) << 2;
                ushort4 pk;
                pk.x = f2bf(sreg[i].x); pk.y = f2bf(sreg[i].y);
                pk.z = f2bf(sreg[i].z); pk.w = f2bf(sreg[i].w);
                *(ushort4*)&X[r * X_P + c] = pk;
                XT[(c + 0) * T_P + r] = pk.x;
                XT[(c + 1) * T_P + r] = pk.y;
                XT[(c + 2) * T_P + r] = pk.z;
                XT[(c + 3) * T_P + r] = pk.w;
            }
        }

        barrier_lds();   // (A) X/XT = x_tr(it+1) ready
    }
}

extern "C" void kernel_launch(void* const* d_in, const int* in_sizes, int n_in,
                              void* d_out, int out_size, void* d_ws, size_t ws_size,
                              hipStream_t stream) {
    const float* q  = (const float*)d_in[0];
    const float* k  = (const float*)d_in[1];
    const float* v  = (const float*)d_in[2];
    const float* Wi = (const float*)d_in[3];
    float* out = (float*)d_out;

    int grid = in_sizes[0] / (NSEQ * ND);   // B * H = 192
    hipFuncSetAttribute((const void*)ttt_fused,
                        hipFuncAttributeMaxDynamicSharedMemorySize, SM_TOTAL);
    hipLaunchKernelGGL(ttt_fused, dim3(grid), dim3(1024), SM_TOTAL, stream,
                       q, k, v, Wi, out);
}